// Round 4
// baseline (223.121 us; speedup 1.0000x reference)
//
#include <hip/hip_runtime.h>
#include <stdint.h>

typedef __bf16 bf16x8 __attribute__((ext_vector_type(8)));
typedef __bf16 bf16x4v __attribute__((ext_vector_type(4)));
typedef float  f32x16 __attribute__((ext_vector_type(16)));
typedef float  f32x4t __attribute__((ext_vector_type(4)));
typedef unsigned int u32x2 __attribute__((ext_vector_type(2)));

// ---- ws layout (bytes) ----
#define WS_W1S 0            // 32 chunks  * 1 KB = 32 KB   W1e fragment-swizzled
#define WS_W2S 32768        // 128 chunks * 1 KB = 128 KB  W2 fragment-swizzled
#define WS_R   163840       // 4*256*256 f32 = 1 MiB   Rt[b][n][o] (incl. b1)
#define WS_CT  1212416      // 4*256*256 bf16 = 512 KB Ct[b][m][o]

// ---------------- merged pre-kernel: weights + rank-1 terms ----------------
__global__ __launch_bounds__(256) void prep_all(
    const float* __restrict__ W1, const float* __restrict__ b1,
    const float* __restrict__ W2, const float* __restrict__ node,
    __bf16* __restrict__ w1s, __bf16* __restrict__ w2s,
    float* __restrict__ Rt, __bf16* __restrict__ Ctb) {
    __shared__ float nds[128 * 4];
    const int blk = blockIdx.x;
    if (blk < 40) {                           // ---- weight swizzle part ----
        int t = blk * 256 + threadIdx.x;      // 40*256 = 160 chunks * 64 lanes
        int chunk = t >> 6, lane = t & 63;
        if (chunk < 128) {                    // W2: 4 wid x 16 ks x 2 mb
            int wid = chunk >> 5, ks = (chunk >> 1) & 15, mb = chunk & 1;
            int o = wid * 64 + mb * 32 + (lane & 31);
            int k = ks * 16 + (lane >> 5) * 8;
            const float* src = W2 + o * 256 + k;
            __bf16* dst = w2s + chunk * 512 + lane * 8;
#pragma unroll
            for (int j = 0; j < 8; ++j) dst[j] = (__bf16)src[j];
        } else if (chunk < 160) {             // W1e: 4 wid x 4 ks x 2 mb
            int c1 = chunk - 128;
            int wid = c1 >> 3, ks = (c1 >> 1) & 3, mb = c1 & 1;
            int o = wid * 64 + mb * 32 + (lane & 31);
            int k = ks * 16 + (lane >> 5) * 8;
            const float* src = W1 + o * 320 + k;
            __bf16* dst = w1s + c1 * 512 + lane * 8;
#pragma unroll
            for (int j = 0; j < 8; ++j) dst[j] = (__bf16)src[j];
        }
        return;
    }
    // ---- rank-1 part: rcb = b*64 + jg, 4 j per thread, o = tid ----
    const int rcb = blk - 40;
    const int b = rcb >> 6, j0 = (rcb & 63) << 2;
    const int o = threadIdx.x;
    if (o < 128)
        *(float4*)&nds[o * 4] = *(const float4*)(node + b * 32768 + o * 256 + j0);
    __syncthreads();
    float aR[4] = {0.f, 0.f, 0.f, 0.f};
    float aC[4] = {0.f, 0.f, 0.f, 0.f};
    const float* wr = W1 + o * 320 + 64;
    const float* wc = W1 + o * 320 + 192;
    for (int c4 = 0; c4 < 32; ++c4) {
        float4 wrv = *(const float4*)(wr + c4 * 4);
        float4 wcv = *(const float4*)(wc + c4 * 4);
        const float* wrp = (const float*)&wrv;
        const float* wcp = (const float*)&wcv;
#pragma unroll
        for (int r = 0; r < 4; ++r) {
            f32x4t n4 = *(const f32x4t*)&nds[(c4 * 4 + r) * 4];  // wave-uniform broadcast
#pragma unroll
            for (int q = 0; q < 4; ++q) {
                aR[q] = fmaf(wrp[r], n4[q], aR[q]);
                aC[q] = fmaf(wcp[r], n4[q], aC[q]);
            }
        }
    }
    float bb = b1[o];
#pragma unroll
    for (int j = 0; j < 4; ++j) {
        int idx = ((b * 256 + j0 + j) << 8) + o;
        Rt[idx] = aR[j] + bb;
        Ctb[idx] = (__bf16)aC[j];
    }
}

// ---------------- main fused kernel ----------------
// R4: 3 waves/SIMD. grid 1024 (4b x 4m x 64 n-groups of 4 rows), 768 blocks
// co-resident = 3 blocks/CU. __launch_bounds__(256,3): per-wave UNIFIED
// VGPR+AGPR budget = 170 (gfx950 unified file; R1 post-mortem). Register diet
// to fit: A1 streamed per-iter (not persisted), Rt/Ct fragments loaded inside
// epilogue-1 (L2-resident; 3-wave TLP hides the latency; asm opaque ptr on Ctb
// defeats LICM re-hoist of the it-invariant Ct loads -> would be +32 persistent
// regs), A2q rolling window 64->32 regs (2-ks groups, double-buffered).
// Peak live ~165 unified. SPILL TRIPWIRE: WRITE_SIZE >> 1 MB.
// LDS diet to fit 3 blocks/CU (<=53.3 KB): lds_h1 pad-140 -> exact 512 B rows
// + XOR swizzle (byte ^= (pix&7)<<4; write 8B / read 16B both inside 16B
// units, same involution both sides -> conflict-free), it-count 8->4 shrinks
// lds_p. Total 52736 B * 3 = 158 KB <= 160 KB.
// Raw LDS-only barriers (R3): no cross-wave global hazards; barriers order
// LDS only, global loads stay in flight across them.
__device__ __forceinline__ void lds_barrier() {
    __builtin_amdgcn_sched_barrier(0);
    asm volatile("s_waitcnt lgkmcnt(0)" ::: "memory");
    __builtin_amdgcn_s_barrier();
    __builtin_amdgcn_sched_barrier(0);
}

__device__ inline void zero_acc(f32x16 acc[2][2]) {
#pragma unroll
    for (int i = 0; i < 2; ++i)
#pragma unroll
        for (int j = 0; j < 2; ++j)
#pragma unroll
            for (int k = 0; k < 16; ++k) acc[i][j][k] = 0.f;
}

__global__ __launch_bounds__(256, 3) void fused_main(
    const float* __restrict__ edge, const __bf16* __restrict__ w1s,
    const __bf16* __restrict__ w2s, const float* __restrict__ Rt,
    const __bf16* __restrict__ Ctb, const float* __restrict__ b2,
    const float* __restrict__ W3, const float* __restrict__ b3,
    float* __restrict__ out) {
    __shared__ unsigned int lds_e[64 * 34];   // edge tile [m][e-pair], stride 34 dw
    __shared__ unsigned int lds_h1[64 * 128]; // h1 tile [pix][ch/2], 512 B rows, XOR-swizzled
    __shared__ float lds_p[4 * 64 * 9];       // per-iteration partials [it][pix][slot]
    __shared__ float lds_c[512];              // [0..255]=b2, [256..511]=W3

    const int tid = threadIdx.x;
    const int wid = tid >> 6;
    const int lane = tid & 63;
    const int p31 = lane & 31;
    const int hi = lane >> 5;
    const int obase = wid * 64;
    const unsigned swz = (unsigned)((p31 & 7) << 4);   // h1 XOR-swizzle for this lane's pix rows

    const int blk = blockIdx.x;
    const int b   = blk >> 8;
    const int m0  = ((blk >> 6) & 3) << 6;
    const int n0  = (blk & 63) << 2;

    lds_c[tid] = b2[tid];
    lds_c[256 + tid] = W3[tid];

    const float4* eg = (const float4*)edge;
    const int a_ = tid & 15;
    const int epb = tid >> 4;
    float4 pf[4];

#define PREFETCH(nn)                                                        \
    {                                                                       \
        _Pragma("unroll")                                                   \
        for (int r = 0; r < 2; ++r) {                                       \
            int ep = r * 16 + epb;                                          \
            int f4 = (b * 64 + ep * 2) * 16384 + (nn) * 64 + (m0 >> 2) + a_;\
            pf[r * 2]     = eg[f4];                                         \
            pf[r * 2 + 1] = eg[f4 + 16384];                                 \
        }                                                                   \
    }

    // W2 2-ks group load: chunk = (wid*16 + ksg)*2 + mb, lane-consecutive 16 B
#define LOAD_G(bf, g)                                                       \
    {                                                                       \
        _Pragma("unroll")                                                   \
        for (int ksl = 0; ksl < 2; ++ksl)                                   \
            _Pragma("unroll")                                               \
            for (int mb = 0; mb < 2; ++mb)                                  \
                A2g[bf][ksl][mb] = *(const bf16x8*)(w2_s +                  \
                    ((((wid << 4) + (g) * 2 + ksl) << 1) + mb) * 512 + (lane << 3)); \
    }

    PREFETCH(n0);

    f32x16 acc[2][2];
    bf16x8 A2g[2][2][2];
#pragma unroll 1
    for (int it = 0; it < 4; ++it) {
        const int n = n0 + it;

        // opaque per-iteration address barriers: defeat LICM/CSE of the
        // it-invariant weight/Ct streams (persisting them = reg blowup)
        uint64_t w1a = (uint64_t)w1s;
        asm volatile("" : "+s"(w1a));
        const __bf16* w1_s = (const __bf16*)w1a;
        uint64_t w2a = (uint64_t)w2s;
        asm volatile("" : "+s"(w2a));
        const __bf16* w2_s = (const __bf16*)w2a;
        uint64_t cta = (uint64_t)Ctb;
        asm volatile("" : "+s"(cta));
        const __bf16* ct_s = (const __bf16*)cta;

        // ---- stage pf -> lds_e (transpose to [m][e], bf16) ----
#pragma unroll
        for (int r = 0; r < 2; ++r) {
            int ep = r * 16 + epb;
            const float* p0 = (const float*)&pf[r * 2];
            const float* p1 = (const float*)&pf[r * 2 + 1];
#pragma unroll
            for (int i = 0; i < 4; ++i) {
                union { __bf16 h[2]; unsigned int u; } t;
                t.h[0] = (__bf16)p0[i];
                t.h[1] = (__bf16)p1[i];
                lds_e[(a_ * 4 + i) * 34 + ep] = t.u;
            }
        }
        // ---- next-row HBM prefetch issued EARLY (pf regs dead after stage) ----
        if (it < 3) PREFETCH(n + 1);

        // ---- A1 (W1e) fragments: coalesced stream from L2, transient regs ----
        bf16x8 A1[2][4];
#pragma unroll
        for (int mb = 0; mb < 2; ++mb)
#pragma unroll
            for (int ks = 0; ks < 4; ++ks)
                A1[mb][ks] = *(const bf16x8*)(w1_s +
                    ((((wid << 2) + ks) << 1) + mb) * 512 + (lane << 3));

        lds_barrier();

        // ---- layer 1: W1e(64K) @ edge ----
        zero_acc(acc);
#pragma unroll
        for (int ks = 0; ks < 4; ++ks) {
            bf16x8 B1[2];
#pragma unroll
            for (int nb = 0; nb < 2; ++nb) {
                union { u32x2 d[2]; bf16x8 v; } bb;
                const unsigned int* base = &lds_e[(nb * 32 + p31) * 34 + ks * 8 + hi * 4];
                bb.d[0] = *(const u32x2*)base;
                bb.d[1] = *(const u32x2*)(base + 2);
                B1[nb] = bb.v;
            }
#pragma unroll
            for (int mb = 0; mb < 2; ++mb) {
                acc[mb][0] = __builtin_amdgcn_mfma_f32_32x32x16_bf16(A1[mb][ks], B1[0], acc[mb][0], 0, 0, 0);
                acc[mb][1] = __builtin_amdgcn_mfma_f32_32x32x16_bf16(A1[mb][ks], B1[1], acc[mb][1], 0, 0, 0);
            }
        }

        // ---- epilogue 1: + Rt[n] + Ct (both streamed from L2 here; 3-wave
        //      TLP hides the latency; mb-split halves transient pressure),
        //      relu -> lds_h1 (XOR-swizzled) ----
        const int nRow = (b * 256 + n) << 8;
#pragma unroll
        for (int mb = 0; mb < 2; ++mb) {
            f32x4t Rvv[4];
            bf16x4v Cvv[4][2];
#pragma unroll
            for (int rg = 0; rg < 4; ++rg) {
                int och = obase + mb * 32 + 8 * rg + 4 * hi;
                Rvv[rg] = *(const f32x4t*)(Rt + nRow + och);
#pragma unroll
                for (int nb = 0; nb < 2; ++nb)
                    Cvv[rg][nb] = *(const bf16x4v*)(ct_s +
                        ((b * 256 + m0 + nb * 32 + p31) << 8) + och);
            }
#pragma unroll
            for (int rg = 0; rg < 4; ++rg) {
                int och = obase + mb * 32 + 8 * rg + 4 * hi;
#pragma unroll
                for (int nb = 0; nb < 2; ++nb) {
                    int pix = nb * 32 + p31;
                    bf16x4v Cv = Cvv[rg][nb];
                    union { __bf16 h[4]; u32x2 u; } t;
#pragma unroll
                    for (int rr = 0; rr < 4; ++rr) {
                        float v = acc[mb][nb][rg * 4 + rr] + Rvv[rg][rr] + (float)Cv[rr];
                        t.h[rr] = (__bf16)fmaxf(v, 0.f);
                    }
                    unsigned off = (unsigned)(pix * 512 + och * 2) ^ swz;
                    *(u32x2*)((char*)lds_h1 + off) = t.u;
                }
            }
        }
        // ---- W2 group-0 prefetch overlapping the barrier ----
        LOAD_G(0, 0);
        lds_barrier();

        // ---- layer 2: W2(256K) @ h1, rolling 2-ks streamed window ----
        zero_acc(acc);
        __builtin_amdgcn_s_setprio(1);
#pragma unroll
        for (int g = 0; g < 8; ++g) {
            if (g < 7) LOAD_G((g + 1) & 1, g + 1);
#pragma unroll
            for (int ksl = 0; ksl < 2; ++ksl) {
                const int ksg = g * 2 + ksl;
                bf16x8 B2[2];
#pragma unroll
                for (int nb = 0; nb < 2; ++nb) {
                    unsigned off = (unsigned)((nb * 32 + p31) * 512 + ksg * 32 + hi * 16) ^ swz;
                    B2[nb] = *(const bf16x8*)((const char*)lds_h1 + off);
                }
#pragma unroll
                for (int mb = 0; mb < 2; ++mb) {
                    acc[mb][0] = __builtin_amdgcn_mfma_f32_32x32x16_bf16(A2g[g & 1][ksl][mb], B2[0], acc[mb][0], 0, 0, 0);
                    acc[mb][1] = __builtin_amdgcn_mfma_f32_32x32x16_bf16(A2g[g & 1][ksl][mb], B2[1], acc[mb][1], 0, 0, 0);
                }
            }
        }
        __builtin_amdgcn_s_setprio(0);

        // ---- epilogue 2: +b2, relu, dot W3 -> per-it lds_p slice ----
        float part0 = 0.f, part1 = 0.f;
#pragma unroll
        for (int mb = 0; mb < 2; ++mb) {
#pragma unroll
            for (int rg = 0; rg < 4; ++rg) {
                int och = obase + mb * 32 + 8 * rg + 4 * hi;
                f32x4t b2v = *(const f32x4t*)&lds_c[och];
                f32x4t w3v = *(const f32x4t*)&lds_c[256 + och];
#pragma unroll
                for (int rr = 0; rr < 4; ++rr) {
                    float h0 = fmaxf(acc[mb][0][rg * 4 + rr] + b2v[rr], 0.f);
                    float h1v = fmaxf(acc[mb][1][rg * 4 + rr] + b2v[rr], 0.f);
                    part0 = fmaf(w3v[rr], h0, part0);
                    part1 = fmaf(w3v[rr], h1v, part1);
                }
            }
        }
        lds_p[(it * 64 + 0 * 32 + p31) * 9 + wid * 2 + hi] = part0;
        lds_p[(it * 64 + 1 * 32 + p31) * 9 + wid * 2 + hi] = part1;
    }

    // ---- single final reduction: 256 outputs (4 rows x 64 m), 1/thread ----
    __syncthreads();
    {
        float bb3 = b3[0];
        int row = tid >> 6;           // it 0..3
        int mm  = tid & 63;
        float s = bb3;
#pragma unroll
        for (int k = 0; k < 8; ++k) s += lds_p[(row * 64 + mm) * 9 + k];
        out[((b * 256 + n0 + row) << 8) + m0 + mm] = s;
    }
#undef PREFETCH
#undef LOAD_G
}

extern "C" void kernel_launch(void* const* d_in, const int* in_sizes, int n_in,
                              void* d_out, int out_size, void* d_ws, size_t ws_size,
                              hipStream_t stream) {
    const float* edge = (const float*)d_in[0];
    const float* node = (const float*)d_in[1];
    const float* W1   = (const float*)d_in[2];
    const float* b1   = (const float*)d_in[3];
    const float* W2   = (const float*)d_in[4];
    const float* b2   = (const float*)d_in[5];
    const float* W3   = (const float*)d_in[6];
    const float* b3   = (const float*)d_in[7];
    char* ws = (char*)d_ws;
    __bf16* w1s = (__bf16*)(ws + WS_W1S);
    __bf16* w2s = (__bf16*)(ws + WS_W2S);
    float*  Rt  = (float*)(ws + WS_R);
    __bf16* Ctb = (__bf16*)(ws + WS_CT);

    prep_all<<<296, 256, 0, stream>>>(W1, b1, W2, node, w1s, w2s, Rt, Ctb);
    fused_main<<<1024, 256, 0, stream>>>(edge, w1s, w2s, Rt, Ctb, b2, W3, b3, (float*)d_out);
}

// Round 5
// 170.703 us; speedup vs baseline: 1.3071x; 1.3071x over previous
//
#include <hip/hip_runtime.h>
#include <stdint.h>

typedef __bf16 bf16x8 __attribute__((ext_vector_type(8)));
typedef __bf16 bf16x4v __attribute__((ext_vector_type(4)));
typedef float  f32x16 __attribute__((ext_vector_type(16)));
typedef float  f32x4t __attribute__((ext_vector_type(4)));
typedef unsigned int u32x2 __attribute__((ext_vector_type(2)));

// ---- ws layout (bytes) ----
#define WS_W1S 0            // 32 chunks  * 1 KB = 32 KB   W1e fragment-swizzled
#define WS_W2S 32768        // 128 chunks * 1 KB = 128 KB  W2 fragment-swizzled
#define WS_R   163840       // 4*256*256 f32 = 1 MiB   Rt[b][n][o] (incl. b1)
#define WS_CT  1212416      // 4*256*256 bf16 = 512 KB Ct[b][m][o]

// ---------------- merged pre-kernel: weights + rank-1 terms ----------------
__global__ __launch_bounds__(256) void prep_all(
    const float* __restrict__ W1, const float* __restrict__ b1,
    const float* __restrict__ W2, const float* __restrict__ node,
    __bf16* __restrict__ w1s, __bf16* __restrict__ w2s,
    float* __restrict__ Rt, __bf16* __restrict__ Ctb) {
    __shared__ float nds[128 * 4];
    const int blk = blockIdx.x;
    if (blk < 40) {                           // ---- weight swizzle part ----
        int t = blk * 256 + threadIdx.x;      // 40*256 = 160 chunks * 64 lanes
        int chunk = t >> 6, lane = t & 63;
        if (chunk < 128) {                    // W2: 4 wid x 16 ks x 2 mb
            int wid = chunk >> 5, ks = (chunk >> 1) & 15, mb = chunk & 1;
            int o = wid * 64 + mb * 32 + (lane & 31);
            int k = ks * 16 + (lane >> 5) * 8;
            const float* src = W2 + o * 256 + k;
            __bf16* dst = w2s + chunk * 512 + lane * 8;
#pragma unroll
            for (int j = 0; j < 8; ++j) dst[j] = (__bf16)src[j];
        } else if (chunk < 160) {             // W1e: 4 wid x 4 ks x 2 mb
            int c1 = chunk - 128;
            int wid = c1 >> 3, ks = (c1 >> 1) & 3, mb = c1 & 1;
            int o = wid * 64 + mb * 32 + (lane & 31);
            int k = ks * 16 + (lane >> 5) * 8;
            const float* src = W1 + o * 320 + k;
            __bf16* dst = w1s + c1 * 512 + lane * 8;
#pragma unroll
            for (int j = 0; j < 8; ++j) dst[j] = (__bf16)src[j];
        }
        return;
    }
    // ---- rank-1 part: rcb = b*64 + jg, 4 j per thread, o = tid ----
    const int rcb = blk - 40;
    const int b = rcb >> 6, j0 = (rcb & 63) << 2;
    const int o = threadIdx.x;
    if (o < 128)
        *(float4*)&nds[o * 4] = *(const float4*)(node + b * 32768 + o * 256 + j0);
    __syncthreads();
    float aR[4] = {0.f, 0.f, 0.f, 0.f};
    float aC[4] = {0.f, 0.f, 0.f, 0.f};
    const float* wr = W1 + o * 320 + 64;
    const float* wc = W1 + o * 320 + 192;
    for (int c4 = 0; c4 < 32; ++c4) {
        float4 wrv = *(const float4*)(wr + c4 * 4);
        float4 wcv = *(const float4*)(wc + c4 * 4);
        const float* wrp = (const float*)&wrv;
        const float* wcp = (const float*)&wcv;
#pragma unroll
        for (int r = 0; r < 4; ++r) {
            f32x4t n4 = *(const f32x4t*)&nds[(c4 * 4 + r) * 4];  // wave-uniform broadcast
#pragma unroll
            for (int q = 0; q < 4; ++q) {
                aR[q] = fmaf(wrp[r], n4[q], aR[q]);
                aC[q] = fmaf(wcp[r], n4[q], aC[q]);
            }
        }
    }
    float bb = b1[o];
#pragma unroll
    for (int j = 0; j < 4; ++j) {
        int idx = ((b * 256 + j0 + j) << 8) + o;
        Rt[idx] = aR[j] + bb;
        Ctb[idx] = (__bf16)aC[j];
    }
}

// ---------------- main fused kernel ----------------
// R5: same tile as R3 (64 pix x 256 och x 8 n-rows, grid 512, 2 blocks/CU,
// stride-140 h1, raw LDS-only barriers) but decomposed into 8 waves x 32 och
// (512 threads) instead of 4 x 64. Per-wave state halves (acc 64->32 AGPR,
// A1 16, A2 window 32), so __launch_bounds__(512,4) = 128 unified regs/wave
// fits with margin -> 4 waves/SIMD (vs 2). R1/R4 post-mortem: 64-och waves
// need ~190 unified regs; any 170-cap spills catastrophically (VGPR 84,
// 28-104 MB scratch, MfmaUtil ~12). Finer waves, not tighter budgets.
// SPILL TRIPWIRE: WRITE_SIZE >> 1 MB or VGPR_Count < 90.
// w1s/w2s fragment chunks are indexed via (wid = wid8>>1, mb = wid8&1) --
// prep layout unchanged.
// Raw barriers: no cross-wave global hazards (all global loads -> private
// regs; ws read-only here); only LDS needs ordering. lds_e: write(it+1) after
// barrier2(it) which follows layer-1 reads(it) [each wave drains lgkm before
// s_barrier]. lds_h1: write(it+1) after barrier1(it+1) which follows
// layer-2 reads(it). lds_p: per-it slices, read after final __syncthreads.
__device__ __forceinline__ void lds_barrier() {
    __builtin_amdgcn_sched_barrier(0);
    asm volatile("s_waitcnt lgkmcnt(0)" ::: "memory");
    __builtin_amdgcn_s_barrier();
    __builtin_amdgcn_sched_barrier(0);
}

__device__ inline void zero_acc(f32x16 acc[2]) {
#pragma unroll
    for (int j = 0; j < 2; ++j)
#pragma unroll
        for (int k = 0; k < 16; ++k) acc[j][k] = 0.f;
}

__global__ __launch_bounds__(512, 4) void fused_main(
    const float* __restrict__ edge, const __bf16* __restrict__ w1s,
    const __bf16* __restrict__ w2s, const float* __restrict__ Rt,
    const __bf16* __restrict__ Ctb, const float* __restrict__ b2,
    const float* __restrict__ W3, const float* __restrict__ b3,
    float* __restrict__ out) {
    __shared__ unsigned int lds_e[64 * 34];   // edge tile [m][e-pair], stride 34 dw
    __shared__ unsigned int lds_h1[64 * 140]; // h1 tile [pix][ch/2], stride 140 dw
    __shared__ float lds_p[8 * 64 * 9];       // per-iteration partials [it][pix][slot]
    __shared__ float lds_c[512];              // [0..255]=b2, [256..511]=W3

    const int tid = threadIdx.x;
    const int wid8 = tid >> 6;                 // 0..7, och block = wid8*32
    const int lane = tid & 63;
    const int p31 = lane & 31;
    const int hi = lane >> 5;
    const int ob32 = wid8 << 5;
    const int wsel = wid8 >> 1, msel = wid8 & 1;  // map to prep's (wid, mb)

    const int blk = blockIdx.x;
    const int b   = blk >> 7;
    const int m0  = ((blk >> 5) & 3) << 6;
    const int n0  = (blk & 31) << 3;

    if (tid < 256) lds_c[tid] = b2[tid];
    else           lds_c[tid] = W3[tid - 256];

    const float4* eg = (const float4*)edge;
    const int a_  = tid & 15;     // m-quad within 64-pix tile
    const int epb = tid >> 4;     // 0..31: e-channel pair
    float4 pf[2];

#define PREFETCH(nn)                                                        \
    {                                                                       \
        int f4 = (b * 64 + epb * 2) * 16384 + (nn) * 64 + (m0 >> 2) + a_;   \
        pf[0] = eg[f4];                                                     \
        pf[1] = eg[f4 + 16384];                                             \
    }

    // W2 4-ks quarter load: chunk = (wsel*16 + ksg)*2 + msel, lane-consec 16 B
#define LOAD_Q(bf, q)                                                       \
    {                                                                       \
        _Pragma("unroll")                                                   \
        for (int ksl = 0; ksl < 4; ++ksl)                                   \
            A2q[bf][ksl] = *(const bf16x8*)(w2_s +                          \
                (((wsel * 16 + (q) * 4 + ksl) << 1) + msel) * 512 + (lane << 3)); \
    }

    PREFETCH(n0);

    f32x16 acc[2];
    bf16x8 A2q[2][4];
    for (int it = 0; it < 8; ++it) {
        const int n = n0 + it;

        // opaque per-iteration address barriers: defeat LICM/CSE of the
        // it-invariant weight/Ct streams (persisting them = reg blowup)
        uint64_t w1a = (uint64_t)w1s;
        asm volatile("" : "+s"(w1a));
        const __bf16* w1_s = (const __bf16*)w1a;
        uint64_t w2a = (uint64_t)w2s;
        asm volatile("" : "+s"(w2a));
        const __bf16* w2_s = (const __bf16*)w2a;
        uint64_t cta = (uint64_t)Ctb;
        asm volatile("" : "+s"(cta));
        const __bf16* ct_s = (const __bf16*)cta;

        // ---- stage pf -> lds_e (transpose to [m][e-pair], bf16) ----
        {
            const float* p0 = (const float*)&pf[0];
            const float* p1 = (const float*)&pf[1];
#pragma unroll
            for (int i = 0; i < 4; ++i) {
                union { __bf16 h[2]; unsigned int u; } t;
                t.h[0] = (__bf16)p0[i];
                t.h[1] = (__bf16)p1[i];
                lds_e[(a_ * 4 + i) * 34 + epb] = t.u;
            }
        }
        // ---- next-row HBM prefetch issued EARLY (pf regs dead after stage);
        //      raw barriers don't drain vmcnt, so it flies over them ----
        if (it < 7) PREFETCH(n + 1);

        // ---- A1 (W1e) fragments: coalesced stream from L2, transient ----
        bf16x8 A1[4];
#pragma unroll
        for (int ks = 0; ks < 4; ++ks)
            A1[ks] = *(const bf16x8*)(w1_s +
                (((wsel * 4 + ks) << 1) + msel) * 512 + (lane << 3));

        lds_barrier();

        // ---- layer 1: W1e(64K) @ edge ----
        zero_acc(acc);
#pragma unroll
        for (int ks = 0; ks < 4; ++ks) {
            bf16x8 B1[2];
#pragma unroll
            for (int nb = 0; nb < 2; ++nb) {
                union { u32x2 d[2]; bf16x8 v; } bb;
                const unsigned int* base = &lds_e[(nb * 32 + p31) * 34 + ks * 8 + hi * 4];
                bb.d[0] = *(const u32x2*)base;
                bb.d[1] = *(const u32x2*)(base + 2);
                B1[nb] = bb.v;
            }
            acc[0] = __builtin_amdgcn_mfma_f32_32x32x16_bf16(A1[ks], B1[0], acc[0], 0, 0, 0);
            acc[1] = __builtin_amdgcn_mfma_f32_32x32x16_bf16(A1[ks], B1[1], acc[1], 0, 0, 0);
        }

        // ---- epilogue 1: + Rt[n] + Ct (streamed, L2-hot; 4 waves/SIMD hide
        //      the latency), relu -> lds_h1 ----
        {
            const int nRow = (b * 256 + n) << 8;
            f32x4t Rvv[4];
            bf16x4v Cvv[4][2];
#pragma unroll
            for (int rg = 0; rg < 4; ++rg) {
                int och = ob32 + 8 * rg + 4 * hi;
                Rvv[rg] = *(const f32x4t*)(Rt + nRow + och);
#pragma unroll
                for (int nb = 0; nb < 2; ++nb)
                    Cvv[rg][nb] = *(const bf16x4v*)(ct_s +
                        ((b * 256 + m0 + nb * 32 + p31) << 8) + och);
            }
#pragma unroll
            for (int rg = 0; rg < 4; ++rg) {
                int och = ob32 + 8 * rg + 4 * hi;
#pragma unroll
                for (int nb = 0; nb < 2; ++nb) {
                    int pix = nb * 32 + p31;
                    bf16x4v Cv = Cvv[rg][nb];
                    union { __bf16 h[4]; u32x2 u; } t;
#pragma unroll
                    for (int rr = 0; rr < 4; ++rr) {
                        float v = acc[nb][rg * 4 + rr] + Rvv[rg][rr] + (float)Cv[rr];
                        t.h[rr] = (__bf16)fmaxf(v, 0.f);
                    }
                    *(u32x2*)&lds_h1[pix * 140 + (och >> 1)] = t.u;
                }
            }
        }
        // ---- W2 quarter-0 prefetch overlapping the barrier ----
        LOAD_Q(0, 0);
        lds_barrier();

        // ---- layer 2: W2(256K) @ h1, rolling streamed quarter window ----
        zero_acc(acc);
        __builtin_amdgcn_s_setprio(1);
#pragma unroll
        for (int q = 0; q < 4; ++q) {
            if (q < 3) LOAD_Q((q + 1) & 1, q + 1);
#pragma unroll
            for (int ksl = 0; ksl < 4; ++ksl) {
                const int ksg = q * 4 + ksl;
                bf16x8 B2[2];
#pragma unroll
                for (int nb = 0; nb < 2; ++nb)
                    B2[nb] = *(const bf16x8*)&lds_h1[(nb * 32 + p31) * 140 + ksg * 8 + hi * 4];
                acc[0] = __builtin_amdgcn_mfma_f32_32x32x16_bf16(A2q[q & 1][ksl], B2[0], acc[0], 0, 0, 0);
                acc[1] = __builtin_amdgcn_mfma_f32_32x32x16_bf16(A2q[q & 1][ksl], B2[1], acc[1], 0, 0, 0);
            }
        }
        __builtin_amdgcn_s_setprio(0);

        // ---- epilogue 2: +b2, relu, dot W3 -> cross-half combine -> lds_p ----
        float part0 = 0.f, part1 = 0.f;
#pragma unroll
        for (int rg = 0; rg < 4; ++rg) {
            int och = ob32 + 8 * rg + 4 * hi;
            f32x4t b2v = *(const f32x4t*)&lds_c[och];
            f32x4t w3v = *(const f32x4t*)&lds_c[256 + och];
#pragma unroll
            for (int rr = 0; rr < 4; ++rr) {
                float h0 = fmaxf(acc[0][rg * 4 + rr] + b2v[rr], 0.f);
                float h1v = fmaxf(acc[1][rg * 4 + rr] + b2v[rr], 0.f);
                part0 = fmaf(w3v[rr], h0, part0);
                part1 = fmaf(w3v[rr], h1v, part1);
            }
        }
        // combine hi=0/hi=1 halves (different och rows of same pixel)
        part0 += __shfl_xor(part0, 32);
        part1 += __shfl_xor(part1, 32);
        {
            int pix = hi * 32 + p31;               // hi=0 -> nb0 pix, hi=1 -> nb1 pix
            float val = hi ? part1 : part0;
            lds_p[(it * 64 + pix) * 9 + wid8] = val;
        }
    }

    // ---- single final reduction: 512 outputs (8 rows x 64 m), 1/thread ----
    __syncthreads();
    {
        float bb3 = b3[0];
        int row = tid >> 6;           // it 0..7
        int mm  = tid & 63;
        float s = bb3;
#pragma unroll
        for (int k = 0; k < 8; ++k) s += lds_p[(row * 64 + mm) * 9 + k];
        out[((b * 256 + n0 + row) << 8) + m0 + mm] = s;
    }
#undef PREFETCH
#undef LOAD_Q
}

extern "C" void kernel_launch(void* const* d_in, const int* in_sizes, int n_in,
                              void* d_out, int out_size, void* d_ws, size_t ws_size,
                              hipStream_t stream) {
    const float* edge = (const float*)d_in[0];
    const float* node = (const float*)d_in[1];
    const float* W1   = (const float*)d_in[2];
    const float* b1   = (const float*)d_in[3];
    const float* W2   = (const float*)d_in[4];
    const float* b2   = (const float*)d_in[5];
    const float* W3   = (const float*)d_in[6];
    const float* b3   = (const float*)d_in[7];
    char* ws = (char*)d_ws;
    __bf16* w1s = (__bf16*)(ws + WS_W1S);
    __bf16* w2s = (__bf16*)(ws + WS_W2S);
    float*  Rt  = (float*)(ws + WS_R);
    __bf16* Ctb = (__bf16*)(ws + WS_CT);

    prep_all<<<296, 256, 0, stream>>>(W1, b1, W2, node, w1s, w2s, Rt, Ctb);
    fused_main<<<512, 512, 0, stream>>>(edge, w1s, w2s, Rt, Ctb, b2, W3, b3, (float*)d_out);
}

// Round 6
// 151.466 us; speedup vs baseline: 1.4731x; 1.1270x over previous
//
#include <hip/hip_runtime.h>
#include <stdint.h>

typedef __bf16 bf16x8 __attribute__((ext_vector_type(8)));
typedef __bf16 bf16x4v __attribute__((ext_vector_type(4)));
typedef float  f32x16 __attribute__((ext_vector_type(16)));
typedef float  f32x4t __attribute__((ext_vector_type(4)));
typedef unsigned int u32x2 __attribute__((ext_vector_type(2)));

// ---- ws layout (bytes) ----
#define WS_W1S 0            // 32 chunks  * 1 KB = 32 KB   W1e fragment-swizzled
#define WS_W2S 32768        // 128 chunks * 1 KB = 128 KB  W2 fragment-swizzled
#define WS_R   163840       // 4*256*256 f32 = 1 MiB   Rt[b][n][o] (incl. b1)
#define WS_CT  1212416      // 4*256*256 bf16 = 512 KB Ct[b][m][o]

// ---------------- merged pre-kernel: weights + rank-1 terms ----------------
__global__ __launch_bounds__(256) void prep_all(
    const float* __restrict__ W1, const float* __restrict__ b1,
    const float* __restrict__ W2, const float* __restrict__ node,
    __bf16* __restrict__ w1s, __bf16* __restrict__ w2s,
    float* __restrict__ Rt, __bf16* __restrict__ Ctb) {
    __shared__ float nds[128 * 4];
    const int blk = blockIdx.x;
    if (blk < 40) {                           // ---- weight swizzle part ----
        int t = blk * 256 + threadIdx.x;      // 40*256 = 160 chunks * 64 lanes
        int chunk = t >> 6, lane = t & 63;
        if (chunk < 128) {                    // W2: 4 wid x 16 ks x 2 mb
            int wid = chunk >> 5, ks = (chunk >> 1) & 15, mb = chunk & 1;
            int o = wid * 64 + mb * 32 + (lane & 31);
            int k = ks * 16 + (lane >> 5) * 8;
            const float* src = W2 + o * 256 + k;
            __bf16* dst = w2s + chunk * 512 + lane * 8;
#pragma unroll
            for (int j = 0; j < 8; ++j) dst[j] = (__bf16)src[j];
        } else if (chunk < 160) {             // W1e: 4 wid x 4 ks x 2 mb
            int c1 = chunk - 128;
            int wid = c1 >> 3, ks = (c1 >> 1) & 3, mb = c1 & 1;
            int o = wid * 64 + mb * 32 + (lane & 31);
            int k = ks * 16 + (lane >> 5) * 8;
            const float* src = W1 + o * 320 + k;
            __bf16* dst = w1s + c1 * 512 + lane * 8;
#pragma unroll
            for (int j = 0; j < 8; ++j) dst[j] = (__bf16)src[j];
        }
        return;
    }
    // ---- rank-1 part: rcb = b*64 + jg, 4 j per thread, o = tid ----
    const int rcb = blk - 40;
    const int b = rcb >> 6, j0 = (rcb & 63) << 2;
    const int o = threadIdx.x;
    if (o < 128)
        *(float4*)&nds[o * 4] = *(const float4*)(node + b * 32768 + o * 256 + j0);
    __syncthreads();
    float aR[4] = {0.f, 0.f, 0.f, 0.f};
    float aC[4] = {0.f, 0.f, 0.f, 0.f};
    const float* wr = W1 + o * 320 + 64;
    const float* wc = W1 + o * 320 + 192;
    for (int c4 = 0; c4 < 32; ++c4) {
        float4 wrv = *(const float4*)(wr + c4 * 4);
        float4 wcv = *(const float4*)(wc + c4 * 4);
        const float* wrp = (const float*)&wrv;
        const float* wcp = (const float*)&wcv;
#pragma unroll
        for (int r = 0; r < 4; ++r) {
            f32x4t n4 = *(const f32x4t*)&nds[(c4 * 4 + r) * 4];  // wave-uniform broadcast
#pragma unroll
            for (int q = 0; q < 4; ++q) {
                aR[q] = fmaf(wrp[r], n4[q], aR[q]);
                aC[q] = fmaf(wcp[r], n4[q], aC[q]);
            }
        }
    }
    float bb = b1[o];
#pragma unroll
    for (int j = 0; j < 4; ++j) {
        int idx = ((b * 256 + j0 + j) << 8) + o;
        Rt[idx] = aR[j] + bb;
        Ctb[idx] = (__bf16)aC[j];
    }
}

// ---------------- main fused kernel ----------------
// R6 = R3 structure (the measured optimum of this family) + accumulator
// preloading. Geometry: 256 thr (4 waves x 64 och), grid 512, 8 n-rows/block,
// 2 blocks/CU, 2 waves/SIMD. Register state: 124 arch + 128 acc = 252 of the
// 256/wave unified budget (gfx950 VGPR+AGPR one file) -> ZERO headroom; do
// not add persistent registers (R1/R4: any cap below demand = 28-104 MB
// scratch, MfmaUtil ~12). R5: halving wave width to raise occupancy doubles
// per-SIMD LDS traffic + per-wave overhead -> 35% slower. Fat waves win.
// R6 change: MFMA's C-operand is a free adder. acc1 preloaded with Ct
// (persisted CvR regs), acc2 preloaded with b2 (LDS broadcast) -> kills both
// zero_acc passes, the +Ct/+b2 adds, and epi2's b2 LDS reads (~384 VALU
// insts/wave/iter, ~1/3 of VALU issue).
// Raw LDS-only barriers (R3): no cross-wave global hazards; barriers order
// LDS only, global loads (HBM edge prefetch, L2 W2 stream) fly across them.
__device__ __forceinline__ void lds_barrier() {
    __builtin_amdgcn_sched_barrier(0);
    asm volatile("s_waitcnt lgkmcnt(0)" ::: "memory");
    __builtin_amdgcn_s_barrier();
    __builtin_amdgcn_sched_barrier(0);
}

__global__ __launch_bounds__(256, 2) void fused_main(
    const float* __restrict__ edge, const __bf16* __restrict__ w1s,
    const __bf16* __restrict__ w2s, const float* __restrict__ Rt,
    const __bf16* __restrict__ Ctb, const float* __restrict__ b2,
    const float* __restrict__ W3, const float* __restrict__ b3,
    float* __restrict__ out) {
    __shared__ unsigned int lds_e[64 * 34];   // edge tile [m][e-pair], stride 34 dw
    __shared__ unsigned int lds_h1[64 * 140]; // h1 tile [pix][ch/2], stride 140 dw
    __shared__ float lds_p[8 * 64 * 9];       // per-iteration partials [it][pix][slot]
    __shared__ float lds_c[512];              // [0..255]=b2, [256..511]=W3

    const int tid = threadIdx.x;
    const int wid = tid >> 6;
    const int lane = tid & 63;
    const int p31 = lane & 31;
    const int hi = lane >> 5;
    const int obase = wid * 64;

    const int blk = blockIdx.x;
    const int b   = blk >> 7;
    const int m0  = ((blk >> 5) & 3) << 6;
    const int n0  = (blk & 31) << 3;

    lds_c[tid] = b2[tid];
    lds_c[256 + tid] = W3[tid];

    const float4* eg = (const float4*)edge;
    const int a_ = tid & 15;
    const int epb = tid >> 4;
    float4 pf[4];

#define PREFETCH(nn)                                                        \
    {                                                                       \
        _Pragma("unroll")                                                   \
        for (int r = 0; r < 2; ++r) {                                       \
            int ep = r * 16 + epb;                                          \
            int f4 = (b * 64 + ep * 2) * 16384 + (nn) * 64 + (m0 >> 2) + a_;\
            pf[r * 2]     = eg[f4];                                         \
            pf[r * 2 + 1] = eg[f4 + 16384];                                 \
        }                                                                   \
    }

    // coalesced: chunk = (wid*16 + ksg)*2 + mb, lane-consecutive 16 B
#define LOAD_Q(bf, q)                                                       \
    {                                                                       \
        _Pragma("unroll")                                                   \
        for (int ksl = 0; ksl < 4; ++ksl)                                   \
            _Pragma("unroll")                                               \
            for (int mb = 0; mb < 2; ++mb)                                  \
                A2q[bf][ksl][mb] = *(const bf16x8*)(w2_s +                  \
                    ((((wid << 4) + (q) * 4 + ksl) << 1) + mb) * 512 + (lane << 3)); \
    }

    PREFETCH(n0);

    // ---- hoisted it-invariant Ct fragments (32 regs, gather once/block) ----
    bf16x4v CvR[8][2];
#pragma unroll
    for (int mb = 0; mb < 2; ++mb)
#pragma unroll
        for (int rg = 0; rg < 4; ++rg)
#pragma unroll
            for (int nb = 0; nb < 2; ++nb)
                CvR[mb * 4 + rg][nb] = *(const bf16x4v*)(Ctb +
                    ((b * 256 + m0 + nb * 32 + p31) << 8) + obase + mb * 32 + 8 * rg + 4 * hi);

    // ---- A1 (W1e) fragments: loop-invariant, persist in regs (32 VGPR) ----
    bf16x8 A1[2][4];
#pragma unroll
    for (int mb = 0; mb < 2; ++mb)
#pragma unroll
        for (int ks = 0; ks < 4; ++ks)
            A1[mb][ks] = *(const bf16x8*)(w1s +
                ((((wid << 2) + ks) << 1) + mb) * 512 + (lane << 3));

    f32x16 acc[2][2];
    bf16x8 A2q[2][4][2];
    for (int it = 0; it < 8; ++it) {
        const int n = n0 + it;

        // opaque per-iteration address barrier: defeat LICM/CSE of W2 loads
        // (full A2q persistence = 128 regs -> spill; A1 is only 32, persisted)
        uint64_t w2a = (uint64_t)w2s;
        asm volatile("" : "+s"(w2a));
        const __bf16* w2_s = (const __bf16*)w2a;

        // ---- stage pf -> lds_e (transpose to [m][e], bf16) ----
#pragma unroll
        for (int r = 0; r < 2; ++r) {
            int ep = r * 16 + epb;
            const float* p0 = (const float*)&pf[r * 2];
            const float* p1 = (const float*)&pf[r * 2 + 1];
#pragma unroll
            for (int i = 0; i < 4; ++i) {
                union { __bf16 h[2]; unsigned int u; } t;
                t.h[0] = (__bf16)p0[i];
                t.h[1] = (__bf16)p1[i];
                lds_e[(a_ * 4 + i) * 34 + ep] = t.u;
            }
        }
        // ---- next-row HBM prefetch issued EARLY (pf regs dead after stage);
        //      ~900cy latency spans barrier1+layer1+epi1+barrier2 ----
        if (it < 7) PREFETCH(n + 1);

        // ---- Rt row prefetch (L2 broadcast), consumed in epilogue 1 ----
        const int nRow = (b * 256 + n) << 8;
        f32x4t Rv[2][4];
#pragma unroll
        for (int mb = 0; mb < 2; ++mb)
#pragma unroll
            for (int rg = 0; rg < 4; ++rg)
                Rv[mb][rg] = *(const f32x4t*)(Rt + nRow + obase + mb * 32 + 8 * rg + 4 * hi);

        // ---- acc1 preload = Ct (C-operand is a free adder: replaces
        //      zero_acc + the +Cv add in epi1; pure reg VALU, overlaps the
        //      barrier wait) ----
#pragma unroll
        for (int mb = 0; mb < 2; ++mb)
#pragma unroll
            for (int nb = 0; nb < 2; ++nb)
#pragma unroll
                for (int rg = 0; rg < 4; ++rg)
#pragma unroll
                    for (int rr = 0; rr < 4; ++rr)
                        acc[mb][nb][rg * 4 + rr] = (float)CvR[mb * 4 + rg][nb][rr];

        lds_barrier();

        // ---- layer 1: W1e(64K) @ edge ----
        __builtin_amdgcn_s_setprio(1);
#pragma unroll
        for (int ks = 0; ks < 4; ++ks) {
            bf16x8 B1[2];
#pragma unroll
            for (int nb = 0; nb < 2; ++nb) {
                union { u32x2 d[2]; bf16x8 v; } bb;
                const unsigned int* base = &lds_e[(nb * 32 + p31) * 34 + ks * 8 + hi * 4];
                bb.d[0] = *(const u32x2*)base;
                bb.d[1] = *(const u32x2*)(base + 2);
                B1[nb] = bb.v;
            }
#pragma unroll
            for (int mb = 0; mb < 2; ++mb) {
                acc[mb][0] = __builtin_amdgcn_mfma_f32_32x32x16_bf16(A1[mb][ks], B1[0], acc[mb][0], 0, 0, 0);
                acc[mb][1] = __builtin_amdgcn_mfma_f32_32x32x16_bf16(A1[mb][ks], B1[1], acc[mb][1], 0, 0, 0);
            }
        }
        __builtin_amdgcn_s_setprio(0);

        // ---- epilogue 1: + Rt[n] (Ct already in acc), relu -> lds_h1 ----
#pragma unroll
        for (int mb = 0; mb < 2; ++mb) {
#pragma unroll
            for (int rg = 0; rg < 4; ++rg) {
                int och = obase + mb * 32 + 8 * rg + 4 * hi;
                f32x4t Rvv = Rv[mb][rg];
#pragma unroll
                for (int nb = 0; nb < 2; ++nb) {
                    int pix = nb * 32 + p31;
                    union { __bf16 h[4]; u32x2 u; } t;
#pragma unroll
                    for (int rr = 0; rr < 4; ++rr) {
                        float v = acc[mb][nb][rg * 4 + rr] + Rvv[rr];
                        t.h[rr] = (__bf16)fmaxf(v, 0.f);
                    }
                    *(u32x2*)&lds_h1[pix * 140 + (och >> 1)] = t.u;
                }
            }
        }
        // ---- W2 quarter-0 prefetch overlapping the barrier ----
        LOAD_Q(0, 0);

        // ---- acc2 preload = b2 (replaces zero_acc + both +b2 adds in epi2;
        //      lds_c reads are 2-address broadcasts = conflict-free) ----
#pragma unroll
        for (int mb = 0; mb < 2; ++mb)
#pragma unroll
            for (int rg = 0; rg < 4; ++rg) {
                f32x4t b2v = *(const f32x4t*)&lds_c[obase + mb * 32 + 8 * rg + 4 * hi];
#pragma unroll
                for (int nb = 0; nb < 2; ++nb)
#pragma unroll
                    for (int rr = 0; rr < 4; ++rr)
                        acc[mb][nb][rg * 4 + rr] = b2v[rr];
            }

        lds_barrier();

        // ---- layer 2: W2(256K) @ h1, rolling streamed quarter window ----
        __builtin_amdgcn_s_setprio(1);
#pragma unroll
        for (int q = 0; q < 4; ++q) {
            if (q < 3) LOAD_Q((q + 1) & 1, q + 1);
#pragma unroll
            for (int ksl = 0; ksl < 4; ++ksl) {
                const int ksg = q * 4 + ksl;
                bf16x8 B2[2];
#pragma unroll
                for (int nb = 0; nb < 2; ++nb)
                    B2[nb] = *(const bf16x8*)&lds_h1[(nb * 32 + p31) * 140 + ksg * 8 + hi * 4];
#pragma unroll
                for (int mb = 0; mb < 2; ++mb) {
                    acc[mb][0] = __builtin_amdgcn_mfma_f32_32x32x16_bf16(A2q[q & 1][ksl][mb], B2[0], acc[mb][0], 0, 0, 0);
                    acc[mb][1] = __builtin_amdgcn_mfma_f32_32x32x16_bf16(A2q[q & 1][ksl][mb], B2[1], acc[mb][1], 0, 0, 0);
                }
            }
        }
        __builtin_amdgcn_s_setprio(0);

        // ---- epilogue 2: relu (b2 already in acc), dot W3 -> per-it lds_p ----
        float part0 = 0.f, part1 = 0.f;
#pragma unroll
        for (int mb = 0; mb < 2; ++mb) {
#pragma unroll
            for (int rg = 0; rg < 4; ++rg) {
                int och = obase + mb * 32 + 8 * rg + 4 * hi;
                f32x4t w3v = *(const f32x4t*)&lds_c[256 + och];
#pragma unroll
                for (int rr = 0; rr < 4; ++rr) {
                    float h0 = fmaxf(acc[mb][0][rg * 4 + rr], 0.f);
                    float h1v = fmaxf(acc[mb][1][rg * 4 + rr], 0.f);
                    part0 = fmaf(w3v[rr], h0, part0);
                    part1 = fmaf(w3v[rr], h1v, part1);
                }
            }
        }
        lds_p[(it * 64 + 0 * 32 + p31) * 9 + wid * 2 + hi] = part0;
        lds_p[(it * 64 + 1 * 32 + p31) * 9 + wid * 2 + hi] = part1;
    }

    // ---- single final reduction: 512 outputs (8 rows x 64 m), 2/thread ----
    __syncthreads();
    {
        float bb3 = b3[0];
#pragma unroll
        for (int r = 0; r < 2; ++r) {
            int idx = r * 256 + tid;      // 0..511
            int row = idx >> 6;           // it 0..7
            int mm  = idx & 63;
            float s = bb3;
#pragma unroll
            for (int k = 0; k < 8; ++k) s += lds_p[(row * 64 + mm) * 9 + k];
            out[((b * 256 + n0 + row) << 8) + m0 + mm] = s;
        }
    }
#undef PREFETCH
#undef LOAD_Q
}

extern "C" void kernel_launch(void* const* d_in, const int* in_sizes, int n_in,
                              void* d_out, int out_size, void* d_ws, size_t ws_size,
                              hipStream_t stream) {
    const float* edge = (const float*)d_in[0];
    const float* node = (const float*)d_in[1];
    const float* W1   = (const float*)d_in[2];
    const float* b1   = (const float*)d_in[3];
    const float* W2   = (const float*)d_in[4];
    const float* b2   = (const float*)d_in[5];
    const float* W3   = (const float*)d_in[6];
    const float* b3   = (const float*)d_in[7];
    char* ws = (char*)d_ws;
    __bf16* w1s = (__bf16*)(ws + WS_W1S);
    __bf16* w2s = (__bf16*)(ws + WS_W2S);
    float*  Rt  = (float*)(ws + WS_R);
    __bf16* Ctb = (__bf16*)(ws + WS_CT);

    prep_all<<<296, 256, 0, stream>>>(W1, b1, W2, node, w1s, w2s, Rt, Ctb);
    fused_main<<<512, 256, 0, stream>>>(edge, w1s, w2s, Rt, Ctb, b2, W3, b3, (float*)d_out);
}

// Round 7
// 148.585 us; speedup vs baseline: 1.5016x; 1.0194x over previous
//
#include <hip/hip_runtime.h>
#include <stdint.h>

typedef __bf16 bf16x8 __attribute__((ext_vector_type(8)));
typedef __bf16 bf16x4v __attribute__((ext_vector_type(4)));
typedef float  f32x16 __attribute__((ext_vector_type(16)));
typedef float  f32x4t __attribute__((ext_vector_type(4)));
typedef unsigned int u32x2 __attribute__((ext_vector_type(2)));

// ---- ws layout (bytes) ----
#define WS_W1S 0            // 32 chunks  * 1 KB = 32 KB   W1e fragment-swizzled
#define WS_W2S 32768        // 128 chunks * 1 KB = 128 KB  W2 fragment-swizzled
#define WS_R   163840       // 4*256*256 f32 = 1 MiB   Rt[b][n][o] (incl. b1)
#define WS_CT  1212416      // 4*256*256 bf16 = 512 KB Ct[b][m][o]

// ---------------- merged pre-kernel: weights + rank-1 + out-init ----------
// blocks 0..39: weight swizzle; 40..295: rank-1 R/C; 296..551: out = b3
// (fused_main now accumulates into out via atomicAdd -> needs init).
__global__ __launch_bounds__(256) void prep_all(
    const float* __restrict__ W1, const float* __restrict__ b1,
    const float* __restrict__ W2, const float* __restrict__ node,
    const float* __restrict__ b3, __bf16* __restrict__ w1s,
    __bf16* __restrict__ w2s, float* __restrict__ Rt,
    __bf16* __restrict__ Ctb, float* __restrict__ out) {
    __shared__ float nds[128 * 4];
    const int blk = blockIdx.x;
    if (blk >= 296) {                         // ---- out-init: 256 blk x 1KB ----
        float v = b3[0];
        float4 f4 = make_float4(v, v, v, v);
        *(float4*)(out + (blk - 296) * 1024 + threadIdx.x * 4) = f4;
        return;
    }
    if (blk < 40) {                           // ---- weight swizzle part ----
        int t = blk * 256 + threadIdx.x;      // 40*256 = 160 chunks * 64 lanes
        int chunk = t >> 6, lane = t & 63;
        if (chunk < 128) {                    // W2: 4 wid x 16 ks x 2 mb
            int wid = chunk >> 5, ks = (chunk >> 1) & 15, mb = chunk & 1;
            int o = wid * 64 + mb * 32 + (lane & 31);
            int k = ks * 16 + (lane >> 5) * 8;
            const float* src = W2 + o * 256 + k;
            __bf16* dst = w2s + chunk * 512 + lane * 8;
#pragma unroll
            for (int j = 0; j < 8; ++j) dst[j] = (__bf16)src[j];
        } else if (chunk < 160) {             // W1e: 4 wid x 4 ks x 2 mb
            int c1 = chunk - 128;
            int wid = c1 >> 3, ks = (c1 >> 1) & 3, mb = c1 & 1;
            int o = wid * 64 + mb * 32 + (lane & 31);
            int k = ks * 16 + (lane >> 5) * 8;
            const float* src = W1 + o * 320 + k;
            __bf16* dst = w1s + c1 * 512 + lane * 8;
#pragma unroll
            for (int j = 0; j < 8; ++j) dst[j] = (__bf16)src[j];
        }
        return;
    }
    // ---- rank-1 part: rcb = b*64 + jg, 4 j per thread, o = tid ----
    const int rcb = blk - 40;
    const int b = rcb >> 6, j0 = (rcb & 63) << 2;
    const int o = threadIdx.x;
    if (o < 128)
        *(float4*)&nds[o * 4] = *(const float4*)(node + b * 32768 + o * 256 + j0);
    __syncthreads();
    float aR[4] = {0.f, 0.f, 0.f, 0.f};
    float aC[4] = {0.f, 0.f, 0.f, 0.f};
    const float* wr = W1 + o * 320 + 64;
    const float* wc = W1 + o * 320 + 192;
    for (int c4 = 0; c4 < 32; ++c4) {
        float4 wrv = *(const float4*)(wr + c4 * 4);
        float4 wcv = *(const float4*)(wc + c4 * 4);
        const float* wrp = (const float*)&wrv;
        const float* wcp = (const float*)&wcv;
#pragma unroll
        for (int r = 0; r < 4; ++r) {
            f32x4t n4 = *(const f32x4t*)&nds[(c4 * 4 + r) * 4];
#pragma unroll
            for (int q = 0; q < 4; ++q) {
                aR[q] = fmaf(wrp[r], n4[q], aR[q]);
                aC[q] = fmaf(wcp[r], n4[q], aC[q]);
            }
        }
    }
    float bb = b1[o];
#pragma unroll
    for (int j = 0; j < 4; ++j) {
        int idx = ((b * 256 + j0 + j) << 8) + o;
        Rt[idx] = aR[j] + bb;
        Ctb[idx] = (__bf16)aC[j];
    }
}

// ---------------- main fused kernel ----------------
// R7: attack the W2 L2 stream (256 KB/CU-iter ~ 4600cy, co-equal with MFMA's
// 5120cy and phase-serialized against it; 512 MB total L2 reads of a 128 KB
// matrix). 512 thr = 8 FAT waves (4 och-groups x 2 n-rows) -- each wave keeps
// R6's exact economics (64 och x 64 pix, acc 64, 80 MFMA/iter; R5 proved thin
// waves lose). 1 block/CU, LDS 153 KB: W2 ksg 8..15 resident in LDS (64 KB,
// staged once in prologue -> zero L2 in loop), ksg 0..7 streamed. W2 L2/row:
// 128 KB -> 32 KB. Barriers/row halve (2 per 2-row iter). Grid 256 = 1/CU,
// 8 iters x 2 rows = 16 rows per block.
// Output: per-wave W3-partials -> __shfl_xor(32) combine -> atomicAdd to out
// (pre-init b3 by prep_all). Kills lds_p + final reduction.
// Budget: (512,2) = 256 unified regs/wave (gfx950 VGPR+AGPR one file). Live
// ~210 incl 64 acc. SPILL TRIPWIRE: WRITE_SIZE >> 10 MB (atomics alone ~5 MB)
// or arch VGPR < 110. Anti-LICM: per-iter opaque koff on resident LDS reads
// (hoisting 16 b128 = +128 regs = spill), opaque w2a on the stream.
// Raw LDS-only barriers: no cross-wave global hazards (atomics are
// fire-and-forget to disjoint-per-lane addresses; out never read here).
// Hazards: lds_e write(itp) .. bar1 .. layer1 read(itp) .. bar2 .. write(itp+1);
// h1[rw] write(epi1,itp) .. bar2 .. read(layer2,itp) .. bar1(itp+1) .. write;
// w2lds written prologue, read after bar1+bar2 of itp0 (lgkm drained at each).
__device__ __forceinline__ void lds_barrier() {
    __builtin_amdgcn_sched_barrier(0);
    asm volatile("s_waitcnt lgkmcnt(0)" ::: "memory");
    __builtin_amdgcn_s_barrier();
    __builtin_amdgcn_sched_barrier(0);
}

__global__ __launch_bounds__(512, 2) void fused_main(
    const float* __restrict__ edge, const __bf16* __restrict__ w1s,
    const __bf16* __restrict__ w2s, const float* __restrict__ Rt,
    const __bf16* __restrict__ Ctb, const float* __restrict__ b2,
    const float* __restrict__ W3, const float* __restrict__ b3,
    float* __restrict__ out) {
    __shared__ __bf16 w2lds[32768];              // 64 KB: W2 ksg 8..15, chunk-linear
    __shared__ unsigned int lds_e[128 * 34];     // 17.4 KB: 2 rows x [64 m][32 ep]
    __shared__ unsigned int lds_h1[2][64 * 140]; // 71.7 KB: per-row h1, stride 140 dw
    __shared__ float lds_c[512];                 // 2 KB: [0..255]=b2, [256..511]=W3

    const int tid = threadIdx.x;
    const int wid8 = tid >> 6;       // 0..7
    const int og   = wid8 & 3;       // och group (64 och)
    const int rw   = wid8 >> 2;      // row within pair (== tid>>8)
    const int lane = tid & 63;
    const int p31  = lane & 31;
    const int hi   = lane >> 5;
    const int obase = og << 6;

    const int blk = blockIdx.x;      // 256 = 4b x 4m x 16 n-groups
    const int b   = blk >> 6;
    const int m0  = ((blk >> 4) & 3) << 6;
    const int n0  = (blk & 15) << 4; // 16 rows per block

    lds_c[tid] = (tid < 256) ? b2[tid] : W3[tid - 256];

    // ---- stage resident W2 half (ksg 8..15) into LDS, ONCE (prologue;
    //      reg-staged: one-time cost, no global_load_lds needed) ----
    {
        bf16x8 wt[8];
#pragma unroll
        for (int i = 0; i < 8; ++i) {
            int rc = wid8 * 8 + i;                     // resident chunk 0..63
            int mb = rc & 1, k8 = (rc >> 1) & 7, wg = rc >> 4;
            int schunk = (((wg << 4) + 8 + k8) << 1) + mb;
            wt[i] = *(const bf16x8*)(w2s + schunk * 512 + (lane << 3));
        }
#pragma unroll
        for (int i = 0; i < 8; ++i)
            *(bf16x8*)(w2lds + (wid8 * 8 + i) * 512 + (lane << 3)) = wt[i];
    }

    const float4* eg = (const float4*)edge;
    const int tid8 = tid & 255;      // within-row thread
    const int a_   = tid8 & 15;      // m-quad
    const int epb  = tid8 >> 4;      // 0..15 e-pair group
    float4 pf[4];

#define PREFETCH(nn)                                                        \
    {                                                                       \
        _Pragma("unroll")                                                   \
        for (int r = 0; r < 2; ++r) {                                       \
            int ep = r * 16 + epb;                                          \
            int f4 = (b * 64 + ep * 2) * 16384 + (nn) * 64 + (m0 >> 2) + a_;\
            pf[r * 2]     = eg[f4];                                         \
            pf[r * 2 + 1] = eg[f4 + 16384];                                 \
        }                                                                   \
    }

    // streamed W2 quarter (ksg 0..7): chunk = ((og*16 + q*4 + ksl)*2 + mb)
#define LOAD_Q(bf, q)                                                       \
    {                                                                       \
        _Pragma("unroll")                                                   \
        for (int ksl = 0; ksl < 4; ++ksl)                                   \
            _Pragma("unroll")                                               \
            for (int mb = 0; mb < 2; ++mb)                                  \
                A2q[bf][ksl][mb] = *(const bf16x8*)(w2_s +                  \
                    ((((og << 4) + (q) * 4 + ksl) << 1) + mb) * 512 + (lane << 3)); \
    }

    PREFETCH(n0 + rw);

    // ---- hoisted it-invariant Ct fragments (32 regs; m-pix only, row-indep) ----
    bf16x4v CvR[8][2];
#pragma unroll
    for (int mb = 0; mb < 2; ++mb)
#pragma unroll
        for (int rg = 0; rg < 4; ++rg)
#pragma unroll
            for (int nb = 0; nb < 2; ++nb)
                CvR[mb * 4 + rg][nb] = *(const bf16x4v*)(Ctb +
                    ((b * 256 + m0 + nb * 32 + p31) << 8) + obase + mb * 32 + 8 * rg + 4 * hi);

    // ---- A1 (W1e) fragments: loop-invariant, persist (32 regs) ----
    bf16x8 A1[2][4];
#pragma unroll
    for (int mb = 0; mb < 2; ++mb)
#pragma unroll
        for (int ks = 0; ks < 4; ++ks)
            A1[mb][ks] = *(const bf16x8*)(w1s +
                ((((og << 2) + ks) << 1) + mb) * 512 + (lane << 3));

    f32x16 acc[2][2];
    bf16x8 A2q[2][4][2];
#pragma unroll 1
    for (int itp = 0; itp < 8; ++itp) {
        const int n_r = n0 + itp * 2 + rw;   // this wave's row

        // opaque per-iteration values: defeat LICM/CSE of streamed W2 loads
        // and of the it-invariant resident LDS reads (hoist = reg blowup)
        uint64_t w2a = (uint64_t)w2s;
        asm volatile("" : "+s"(w2a));
        const __bf16* w2_s = (const __bf16*)w2a;
        int koff = 0;
        asm volatile("" : "+v"(koff));

        // ---- stage pf -> lds_e (transpose to [m][e-pair], bf16), own row ----
#pragma unroll
        for (int r = 0; r < 2; ++r) {
            int ep = r * 16 + epb;
            const float* p0 = (const float*)&pf[r * 2];
            const float* p1 = (const float*)&pf[r * 2 + 1];
#pragma unroll
            for (int i = 0; i < 4; ++i) {
                union { __bf16 h[2]; unsigned int u; } t;
                t.h[0] = (__bf16)p0[i];
                t.h[1] = (__bf16)p1[i];
                lds_e[(rw * 64 + a_ * 4 + i) * 34 + ep] = t.u;
            }
        }
        // ---- next-pair HBM prefetch issued EARLY (flies across barriers) ----
        if (itp < 7) PREFETCH(n0 + (itp + 1) * 2 + rw);

        // ---- Rt row (L2 broadcast), consumed in epilogue 1 ----
        const int nRow = (b * 256 + n_r) << 8;
        f32x4t Rv[2][4];
#pragma unroll
        for (int mb = 0; mb < 2; ++mb)
#pragma unroll
            for (int rg = 0; rg < 4; ++rg)
                Rv[mb][rg] = *(const f32x4t*)(Rt + nRow + obase + mb * 32 + 8 * rg + 4 * hi);

        // ---- acc1 preload = Ct (MFMA C-operand is a free adder) ----
#pragma unroll
        for (int mb = 0; mb < 2; ++mb)
#pragma unroll
            for (int nb = 0; nb < 2; ++nb)
#pragma unroll
                for (int rg = 0; rg < 4; ++rg)
#pragma unroll
                    for (int rr = 0; rr < 4; ++rr)
                        acc[mb][nb][rg * 4 + rr] = (float)CvR[mb * 4 + rg][nb][rr];

        lds_barrier();

        // ---- layer 1: W1e(64K) @ edge (own row) ----
        __builtin_amdgcn_s_setprio(1);
#pragma unroll
        for (int ks = 0; ks < 4; ++ks) {
            bf16x8 B1[2];
#pragma unroll
            for (int nb = 0; nb < 2; ++nb) {
                union { u32x2 d[2]; bf16x8 v; } bb;
                const unsigned int* base = &lds_e[(rw * 64 + nb * 32 + p31) * 34 + ks * 8 + hi * 4];
                bb.d[0] = *(const u32x2*)base;
                bb.d[1] = *(const u32x2*)(base + 2);
                B1[nb] = bb.v;
            }
#pragma unroll
            for (int mb = 0; mb < 2; ++mb) {
                acc[mb][0] = __builtin_amdgcn_mfma_f32_32x32x16_bf16(A1[mb][ks], B1[0], acc[mb][0], 0, 0, 0);
                acc[mb][1] = __builtin_amdgcn_mfma_f32_32x32x16_bf16(A1[mb][ks], B1[1], acc[mb][1], 0, 0, 0);
            }
        }
        __builtin_amdgcn_s_setprio(0);

        // ---- epilogue 1: relu(acc + Rt) -> lds_h1[rw] ----
#pragma unroll
        for (int mb = 0; mb < 2; ++mb) {
#pragma unroll
            for (int rg = 0; rg < 4; ++rg) {
                int och = obase + mb * 32 + 8 * rg + 4 * hi;
                f32x4t Rvv = Rv[mb][rg];
#pragma unroll
                for (int nb = 0; nb < 2; ++nb) {
                    int pix = nb * 32 + p31;
                    union { __bf16 h[4]; u32x2 u; } t;
#pragma unroll
                    for (int rr = 0; rr < 4; ++rr) {
                        float v = acc[mb][nb][rg * 4 + rr] + Rvv[rr];
                        t.h[rr] = (__bf16)fmaxf(v, 0.f);
                    }
                    *(u32x2*)&lds_h1[rw][pix * 140 + (och >> 1)] = t.u;
                }
            }
        }
        // ---- streamed W2 quarter-0 prefetch, overlaps the barrier ----
        LOAD_Q(0, 0);

        // ---- acc2 preload = b2 ----
#pragma unroll
        for (int mb = 0; mb < 2; ++mb)
#pragma unroll
            for (int rg = 0; rg < 4; ++rg) {
                f32x4t b2v = *(const f32x4t*)&lds_c[obase + mb * 32 + 8 * rg + 4 * hi];
#pragma unroll
                for (int nb = 0; nb < 2; ++nb)
#pragma unroll
                    for (int rr = 0; rr < 4; ++rr)
                        acc[mb][nb][rg * 4 + rr] = b2v[rr];
            }

        lds_barrier();

        // ---- layer 2: ksg 0..7 streamed (rolling dbuf), 8..15 LDS-resident ----
        __builtin_amdgcn_s_setprio(1);
#pragma unroll
        for (int q = 0; q < 2; ++q) {
            if (q == 0) LOAD_Q(1, 1);
#pragma unroll
            for (int ksl = 0; ksl < 4; ++ksl) {
                const int ksg = q * 4 + ksl;
                bf16x8 B2[2];
#pragma unroll
                for (int nb = 0; nb < 2; ++nb)
                    B2[nb] = *(const bf16x8*)&lds_h1[rw][(nb * 32 + p31) * 140 + ksg * 8 + hi * 4];
#pragma unroll
                for (int mb = 0; mb < 2; ++mb) {
                    acc[mb][0] = __builtin_amdgcn_mfma_f32_32x32x16_bf16(A2q[q][ksl][mb], B2[0], acc[mb][0], 0, 0, 0);
                    acc[mb][1] = __builtin_amdgcn_mfma_f32_32x32x16_bf16(A2q[q][ksl][mb], B2[1], acc[mb][1], 0, 0, 0);
                }
            }
        }
#pragma unroll
        for (int k8 = 0; k8 < 8; ++k8) {
            const int ksg = 8 + k8;
            bf16x8 A2r[2];
#pragma unroll
            for (int mb = 0; mb < 2; ++mb)
                A2r[mb] = *(const bf16x8*)(w2lds +
                    (((og * 8 + k8) * 2 + mb) * 512 + koff) + (lane << 3));
            bf16x8 B2[2];
#pragma unroll
            for (int nb = 0; nb < 2; ++nb)
                B2[nb] = *(const bf16x8*)&lds_h1[rw][(nb * 32 + p31) * 140 + ksg * 8 + hi * 4];
#pragma unroll
            for (int mb = 0; mb < 2; ++mb) {
                acc[mb][0] = __builtin_amdgcn_mfma_f32_32x32x16_bf16(A2r[mb], B2[0], acc[mb][0], 0, 0, 0);
                acc[mb][1] = __builtin_amdgcn_mfma_f32_32x32x16_bf16(A2r[mb], B2[1], acc[mb][1], 0, 0, 0);
            }
        }
        __builtin_amdgcn_s_setprio(0);

        // ---- epilogue 2: relu, dot W3, shfl-combine, atomicAdd out ----
        float part0 = 0.f, part1 = 0.f;
#pragma unroll
        for (int mb = 0; mb < 2; ++mb) {
#pragma unroll
            for (int rg = 0; rg < 4; ++rg) {
                int och = obase + mb * 32 + 8 * rg + 4 * hi;
                f32x4t w3v = *(const f32x4t*)&lds_c[256 + och];
#pragma unroll
                for (int rr = 0; rr < 4; ++rr) {
                    float h0 = fmaxf(acc[mb][0][rg * 4 + rr], 0.f);
                    float h1v = fmaxf(acc[mb][1][rg * 4 + rr], 0.f);
                    part0 = fmaf(w3v[rr], h0, part0);
                    part1 = fmaf(w3v[rr], h1v, part1);
                }
            }
        }
        // combine hi halves (och 0..31 vs 32..63 of this wave's slice)
        part0 += __shfl_xor(part0, 32);
        part1 += __shfl_xor(part1, 32);
        {
            int pix = hi ? (32 + p31) : p31;
            float v = hi ? part1 : part0;
            atomicAdd(&out[((b * 256 + n_r) << 8) + m0 + pix], v);
        }
    }
#undef PREFETCH
#undef LOAD_Q
}

extern "C" void kernel_launch(void* const* d_in, const int* in_sizes, int n_in,
                              void* d_out, int out_size, void* d_ws, size_t ws_size,
                              hipStream_t stream) {
    const float* edge = (const float*)d_in[0];
    const float* node = (const float*)d_in[1];
    const float* W1   = (const float*)d_in[2];
    const float* b1   = (const float*)d_in[3];
    const float* W2   = (const float*)d_in[4];
    const float* b2   = (const float*)d_in[5];
    const float* W3   = (const float*)d_in[6];
    const float* b3   = (const float*)d_in[7];
    char* ws = (char*)d_ws;
    __bf16* w1s = (__bf16*)(ws + WS_W1S);
    __bf16* w2s = (__bf16*)(ws + WS_W2S);
    float*  Rt  = (float*)(ws + WS_R);
    __bf16* Ctb = (__bf16*)(ws + WS_CT);
    float* outp = (float*)d_out;

    prep_all<<<552, 256, 0, stream>>>(W1, b1, W2, node, b3, w1s, w2s, Rt, Ctb, outp);
    fused_main<<<256, 512, 0, stream>>>(edge, w1s, w2s, Rt, Ctb, b2, W3, b3, outp);
}